// Round 2
// baseline (414.364 us; speedup 1.0000x reference)
//
#include <hip/hip_runtime.h>
#include <math.h>

#define B_ 16
#define C_ 3
#define H_ 512
#define W_ 512
#define HW_ (H_*W_)              // 262144
#define HW4 (HW_/4)              // 65536
#define NFULL (B_*C_*HW_)        // 12582912
#define NHALF (B_*HW_)           // 4194304
#define N4 (NFULL/4)             // 3145728
#define M4 (NHALF/4)             // 1048576
#define CHW4 (C_*HW4)            // 196608
#define HW4m (HW4-1)
#define OUTW 506                 // 512-7+1
#define ROWS 32                  // output rows per SSIM strip
#define CW 528                   // padded LDS row width

#define NSSIM 1536               // 96 images x 16 strips
#define NELEM 200
#define NHIST 48
#define NBLK  (NSSIM+NELEM+NHIST)   // 1784

#define INV49 (1.0f/49.0f)
#define COVN  (49.0f/48.0f)
#define C1f   (1e-4f)
#define C2f   (9e-4f)

__device__ __forceinline__ float wred(float v){
  v += __shfl_down(v,32); v += __shfl_down(v,16); v += __shfl_down(v,8);
  v += __shfl_down(v,4);  v += __shfl_down(v,2);  v += __shfl_down(v,1);
  return v;
}

__device__ __forceinline__ void upd5(float4&cx,float4&cy,float4&cxx,float4&cyy,float4&cxy,
                                     const float4 xv,const float4 yv,const float s){
  cx.x += s*xv.x; cx.y += s*xv.y; cx.z += s*xv.z; cx.w += s*xv.w;
  cy.x += s*yv.x; cy.y += s*yv.y; cy.z += s*yv.z; cy.w += s*yv.w;
  cxx.x += s*xv.x*xv.x; cxx.y += s*xv.y*xv.y; cxx.z += s*xv.z*xv.z; cxx.w += s*xv.w*xv.w;
  cyy.x += s*yv.x*yv.x; cyy.y += s*yv.y*yv.y; cyy.z += s*yv.z*yv.z; cyy.w += s*yv.w*yv.w;
  cxy.x += s*xv.x*yv.x; cxy.y += s*xv.y*yv.y; cxy.z += s*xv.z*yv.z; cxy.w += s*xv.w*yv.w;
}

// ---- ONE mega-kernel: block-role specialization so all roles co-run ----
// blocks [0,1536): SSIM (2 pairs x 48 bc x 16 strips)
// blocks [1536,1736): fused elementwise reductions
// blocks [1736,1784): per-(b,c) histograms of target
__global__ __launch_bounds__(128, 4) void k_mega(
    const float* __restrict__ img, const float* __restrict__ tgt,
    const float* __restrict__ c0,  const float* __restrict__ c1,
    const float* __restrict__ c2,  const float* __restrict__ r0,
    const float* __restrict__ r1,
    double* __restrict__ acc, unsigned int* __restrict__ bins){
  __shared__ __align__(16) float smem[2*5*CW + 16];   // 21184 B -> 7 blocks/CU
  const int bid = blockIdx.x;
  const int t   = threadIdx.x;

  if (bid < NSSIM) {
    // ================= SSIM role =================
    const int imgid = bid >> 4;              // 0..95
    const int strip = bid & 15;
    const int pair  = imgid / (B_*C_);       // 0 or 1
    const int bc    = imgid % (B_*C_);
    const float* xim = (pair ? img : c0) + (size_t)bc*HW_;
    const float* yim = (pair ? tgt : r0) + (size_t)bc*HW_;
    const int i0   = strip*ROWS;
    const int iEnd = min(i0+ROWS, OUTW);
    const int c = 4*t;                       // 4 cols per lane

    float* sw = smem + 2*5*CW;               // 2 floats of scratch
    #define LDS(buf,q,cc) smem[(buf)*5*CW + (q)*CW + (cc)]

    float4 cx={0.f,0.f,0.f,0.f}, cy=cx, cxx=cx, cyy=cx, cxy=cx;
    #pragma unroll 1
    for(int r=i0; r<i0+7; ++r){
      float4 xv = *(const float4*)(xim + (size_t)r*W_ + c);
      float4 yv = *(const float4*)(yim + (size_t)r*W_ + c);
      upd5(cx,cy,cxx,cyy,cxy, xv,yv, 1.0f);
    }

    float accS = 0.f;
    for(int i=i0; i<iEnd; ++i){
      const int buf = i&1;
      *(float4*)&LDS(buf,0,c) = cx;
      *(float4*)&LDS(buf,1,c) = cy;
      *(float4*)&LDS(buf,2,c) = cxx;
      *(float4*)&LDS(buf,3,c) = cyy;
      *(float4*)&LDS(buf,4,c) = cxy;
      float4 xn,yn,xo,yo;
      const bool upd = (i+1 < iEnd);
      if(upd){
        xn = *(const float4*)(xim + (size_t)(i+7)*W_ + c);
        yn = *(const float4*)(yim + (size_t)(i+7)*W_ + c);
        xo = *(const float4*)(xim + (size_t)i*W_ + c);
        yo = *(const float4*)(yim + (size_t)i*W_ + c);
      }
      __syncthreads();
      if(c < OUTW){
        float hx[4],hy[4],hxx[4],hyy[4],hxy[4];
        auto hsum=[&](const float* p, float* h){
          float4 A=*(const float4*)p; float4 Bv=*(const float4*)(p+4);
          float2 D=*(const float2*)(p+8);
          float s=A.x+A.y+A.z+A.w+Bv.x+Bv.y+Bv.z;
          h[0]=s; s+=Bv.w-A.x; h[1]=s; s+=D.x-A.y; h[2]=s; s+=D.y-A.z; h[3]=s;
        };
        hsum(&LDS(buf,0,c), hx);
        hsum(&LDS(buf,1,c), hy);
        hsum(&LDS(buf,2,c), hxx);
        hsum(&LDS(buf,3,c), hyy);
        hsum(&LDS(buf,4,c), hxy);
        #pragma unroll
        for(int k=0;k<4;k++){
          if(c+k < OUTW){
            float sx=hx[k], sy=hy[k], sxx=hxx[k], syy=hyy[k], sxy=hxy[k];
            float ux=sx*INV49, uy=sy*INV49;
            float uxuy=ux*uy;
            float vx=COVN*(sxx*INV49-ux*ux);
            float vy=COVN*(syy*INV49-uy*uy);
            float vxy=COVN*(sxy*INV49-uxuy);
            float num=(2.f*uxuy+C1f)*(2.f*vxy+C2f);
            float den=(ux*ux+uy*uy+C1f)*(vx+vy+C2f);
            accS += num/den;
          }
        }
      }
      if(upd){
        upd5(cx,cy,cxx,cyy,cxy, xn,yn,  1.0f);
        upd5(cx,cy,cxx,cyy,cxy, xo,yo, -1.0f);
      }
    }
    float r = wred(accS);
    if((t&63)==0) sw[t>>6]=r;
    __syncthreads();
    if(t==0) atomicAdd(&acc[6+pair], (double)(sw[0]+sw[1]));
    #undef LDS

  } else if (bid < NSSIM+NELEM) {
    // ================= elementwise-reduction role =================
    const int rid = bid - NSSIM;             // 0..199
    const float4* IMG=(const float4*)img; const float4* TGT=(const float4*)tgt;
    const float4* C0=(const float4*)c0;   const float4* C1=(const float4*)c1;
    const float4* C2=(const float4*)c2;   const float4* R0=(const float4*)r0;
    const float4* R1=(const float4*)r1;
    float s0=0.f,s1=0.f,s2=0.f,s3=0.f,s4=0.f;
    // loop1: N4 = 12288 chunks of 256 float4 (2 per thread, consecutive)
    for(int ch=rid; ch<12288; ch+=NELEM){
      const int base = ch*256 + t;
      #pragma unroll
      for(int u=0; u<2; ++u){
        const int m = base + u*128;
        const int b = m / CHW4;
        const int off = m - b*CHW4;
        const int ci = b*HW4 + (off & HW4m);
        float4 a=C0[m], r=R0[m], im=IMG[m], tg=TGT[m], o=C1[ci], q=R1[ci];
        s0 += fabsf(a.x-r.x)+fabsf(a.y-r.y)+fabsf(a.z-r.z)+fabsf(a.w-r.w);
        s1 += fabsf(im.x-a.x*o.x)+fabsf(im.y-a.y*o.y)+fabsf(im.z-a.z*o.z)+fabsf(im.w-a.w*o.w);
        s2 += fabsf(tg.x-r.x*q.x)+fabsf(tg.y-r.y*q.y)+fabsf(tg.z-r.z*q.z)+fabsf(tg.w-r.w*q.w);
        float dx=im.x-tg.x, dy=im.y-tg.y, dz=im.z-tg.z, dw=im.w-tg.w;
        s3 += dx*dx+dy*dy+dz*dz+dw*dw;
      }
    }
    // loop2: M4 = 4096 chunks of 256 float4
    for(int ch=rid; ch<4096; ch+=NELEM){
      const int base = ch*256 + t;
      #pragma unroll
      for(int u=0; u<2; ++u){
        const int m = base + u*128;
        float4 a=C2[m], r=R1[m];
        float dx=a.x-r.x, dy=a.y-r.y, dz=a.z-r.z, dw=a.w-r.w;
        s4 += dx*dx+dy*dy+dz*dz+dw*dw;
      }
    }
    float* sred = smem;                      // [2 waves][5]
    const int wid=t>>6, lane=t&63;
    float v0=wred(s0), v1=wred(s1), v2=wred(s2), v3=wred(s3), v4=wred(s4);
    if(lane==0){ sred[wid*5+0]=v0; sred[wid*5+1]=v1; sred[wid*5+2]=v2;
                 sred[wid*5+3]=v3; sred[wid*5+4]=v4; }
    __syncthreads();
    if(t==0){
      #pragma unroll
      for(int q5=0;q5<5;q5++)
        atomicAdd(&acc[q5], (double)(sred[q5]+sred[5+q5]));
    }

  } else {
    // ================= histogram role =================
    const int imgi = bid - (NSSIM+NELEM);    // 0..47
    unsigned int* sh = (unsigned int*)smem;  // 2 x 256 per-wave sub-hists
    sh[t]=0u; sh[t+128]=0u; sh[t+256]=0u; sh[t+384]=0u;
    __syncthreads();
    unsigned int* mysh = sh + ((t>>6)<<8);
    const float4* t4 = (const float4*)tgt + (size_t)imgi*HW4;
    for(int i=t; i<HW4; i+=128){
      float4 v = t4[i];
      int i0 = __float2int_rn(v.x*255.0f); i0 = min(max(i0,0),255);
      int i1 = __float2int_rn(v.y*255.0f); i1 = min(max(i1,0),255);
      int i2 = __float2int_rn(v.z*255.0f); i2 = min(max(i2,0),255);
      int i3 = __float2int_rn(v.w*255.0f); i3 = min(max(i3,0),255);
      atomicAdd(&mysh[i0],1u); atomicAdd(&mysh[i1],1u);
      atomicAdd(&mysh[i2],1u); atomicAdd(&mysh[i3],1u);
    }
    __syncthreads();
    for(int j=t; j<256; j+=128)
      atomicAdd(&bins[imgi*256+j], sh[j]+sh[256+j]);
  }
}

// ---------------- final combine ----------------
__global__ __launch_bounds__(256) void k_final(
    const float* __restrict__ chist, const float* __restrict__ score,
    const double* __restrict__ acc, const unsigned int* __restrict__ bins,
    float* __restrict__ out){
  const int tid = threadIdx.x;
  float cpart = 0.f;
  for(int i=tid; i<B_*C_*256; i+=256){
    float h = (float)bins[i] * (1.0f/(float)HW_);
    cpart += fabsf(chist[i]-h);
  }
  float gpart = 0.f;
  if(tid < B_){
    float x = -score[tid];
    gpart = (x > 0.f) ? (x + log1pf(expf(-x))) : log1pf(expf(x));
  }
  __shared__ float sc[4], sg[4];
  float rc=wred(cpart), rg=wred(gpart);
  const int wid=tid>>6, lane=tid&63;
  if(lane==0){ sc[wid]=rc; sg[wid]=rg; }
  __syncthreads();
  if(tid==0){
    float colorsum = sc[0]+sc[1]+sc[2]+sc[3];
    float gansum   = sg[0]+sg[1]+sg[2]+sg[3];
    double nfull = (double)NFULL;
    double m0 = acc[0]/nfull, m1 = acc[1]/nfull, m2 = acc[2]/nfull, mse = acc[3]/nfull;
    double light = acc[4]/(double)NHALF;
    double nss = (double)(B_*C_) * (double)OUTW * (double)OUTW;
    double ssimA = acc[6]/nss;   // comp0 vs real_comp0
    double ssimB = acc[7]/nss;   // img vs target
    float r_loss   = (float)((1.0-ssimA)+m0+m1+m2);
    float out_loss = (float)((1.0-ssimB)+mse);
    float color    = colorsum * (1.0f/(float)(B_*C_*256));
    float gan      = gansum * (1.0f/(float)B_);
    float lightf   = (float)light;
    float loss = r_loss + lightf + 0.1f*color + out_loss + 0.05f*gan;
    out[0]=loss; out[1]=loss; out[2]=r_loss; out[3]=lightf;
    out[4]=color; out[5]=out_loss; out[6]=gan;
  }
}

extern "C" void kernel_launch(void* const* d_in, const int* in_sizes, int n_in,
                              void* d_out, int out_size, void* d_ws, size_t ws_size,
                              hipStream_t stream) {
  const float* img    = (const float*)d_in[0];
  const float* target = (const float*)d_in[1];
  const float* comp0  = (const float*)d_in[2];
  const float* comp1  = (const float*)d_in[3];
  const float* comp2  = (const float*)d_in[4];
  const float* rc0    = (const float*)d_in[5];
  const float* rc1    = (const float*)d_in[6];
  const float* chist  = (const float*)d_in[7];
  const float* score  = (const float*)d_in[8];

  double* acc = (double*)d_ws;                                   // 16 doubles
  unsigned int* bins = (unsigned int*)((char*)d_ws + 128);       // 48*256 uints

  hipMemsetAsync(d_ws, 0, 128 + (size_t)B_*C_*256*4, stream);

  k_mega<<<NBLK, 128, 0, stream>>>(img, target, comp0, comp1, comp2,
                                   rc0, rc1, acc, bins);
  k_final<<<1, 256, 0, stream>>>(chist, score, acc, bins, (float*)d_out);
}

// Round 3
// 401.369 us; speedup vs baseline: 1.0324x; 1.0324x over previous
//
#include <hip/hip_runtime.h>
#include <math.h>

#define B_ 16
#define C_ 3
#define H_ 512
#define W_ 512
#define HW_ (H_*W_)              // 262144
#define NFULL (B_*C_*HW_)        // 12582912
#define NHALF (B_*HW_)           // 4194304
#define OUTW 506                 // 512-7+1
#define ROWS 16                  // output rows per strip
#define NSTRIP 32                // 32 strips x 16 rows = 512
#define CW 528                   // padded LDS row width

#define INV49 (1.0f/49.0f)
#define COVN  (49.0f/48.0f)
#define C1f   (1e-4f)
#define C2f   (9e-4f)

__device__ __forceinline__ float wred(float v){
  v += __shfl_down(v,32); v += __shfl_down(v,16); v += __shfl_down(v,8);
  v += __shfl_down(v,4);  v += __shfl_down(v,2);  v += __shfl_down(v,1);
  return v;
}

__device__ __forceinline__ void upd5(float4&cx,float4&cy,float4&cxx,float4&cyy,float4&cxy,
                                     const float4 xv,const float4 yv,const float s){
  cx.x += s*xv.x; cx.y += s*xv.y; cx.z += s*xv.z; cx.w += s*xv.w;
  cy.x += s*yv.x; cy.y += s*yv.y; cy.z += s*yv.z; cy.w += s*yv.w;
  cxx.x += s*xv.x*xv.x; cxx.y += s*xv.y*xv.y; cxx.z += s*xv.z*xv.z; cxx.w += s*xv.w*xv.w;
  cyy.x += s*yv.x*yv.x; cyy.y += s*yv.y*yv.y; cyy.z += s*yv.z*yv.z; cyy.w += s*yv.w*yv.w;
  cxy.x += s*xv.x*yv.x; cxy.y += s*xv.y*yv.y; cxy.z += s*xv.z*yv.z; cxy.w += s*xv.w*yv.w;
}

// One uniform block type: (bc, strip). Computes BOTH SSIM pairs for its rows
// plus all elementwise loss terms and the target histogram from the same data.
__global__ __launch_bounds__(128, 3) void k_mega(
    const float* __restrict__ img, const float* __restrict__ tgt,
    const float* __restrict__ c0,  const float* __restrict__ c1,
    const float* __restrict__ c2,  const float* __restrict__ r0,
    const float* __restrict__ r1,
    double* __restrict__ acc, unsigned int* __restrict__ bins){
  __shared__ __align__(16) float S[2][5][CW];     // buf0 = pair A, buf1 = pair B
  __shared__ unsigned int hist[2][256];           // per-wave sub-hists of tgt
  __shared__ float sred[2][8];

  const int bid = blockIdx.x;
  const int t   = threadIdx.x;
  const int bc    = bid >> 5;       // 0..47
  const int strip = bid & 31;       // 0..31
  const int b  = bc / 3;
  const bool do_c2 = (bc - b*3) == 0;

  const float* xA = c0  + (size_t)bc*HW_;   // comp0
  const float* yA = r0  + (size_t)bc*HW_;   // real_comp0
  const float* xB = img + (size_t)bc*HW_;   // img
  const float* yB = tgt + (size_t)bc*HW_;   // target
  const float* c1b = c1 + (size_t)b*HW_;    // comp1
  const float* r1b = r1 + (size_t)b*HW_;    // real_comp1
  const float* c2b = c2 + (size_t)b*HW_;    // comp2

  const int i0   = strip*ROWS;
  const int iEnd = min(i0+ROWS, OUTW);
  const int eEnd = i0+ROWS;                 // elem rows [i0, eEnd), eEnd<=512
  const int c = 4*t;                        // 4 cols per lane

  hist[0][t]=0u; hist[0][t+128]=0u; hist[1][t]=0u; hist[1][t+128]=0u;
  unsigned int* mysh = hist[t>>6];
  __syncthreads();

  float4 z={0.f,0.f,0.f,0.f};
  float4 AX=z,AY=z,AXX=z,AYY=z,AXY=z;
  float4 BX=z,BY=z,BXX=z,BYY=z,BXY=z;
  float s0=0.f,s1=0.f,s2=0.f,s3=0.f,s4=0.f;

  auto elem_acc=[&](const float4 xa,const float4 ya,const float4 xb,const float4 yb,
                    const float4 cv,const float4 rv){
    s0 += fabsf(xa.x-ya.x)+fabsf(xa.y-ya.y)+fabsf(xa.z-ya.z)+fabsf(xa.w-ya.w);
    s1 += fabsf(xb.x-xa.x*cv.x)+fabsf(xb.y-xa.y*cv.y)+fabsf(xb.z-xa.z*cv.z)+fabsf(xb.w-xa.w*cv.w);
    s2 += fabsf(yb.x-ya.x*rv.x)+fabsf(yb.y-ya.y*rv.y)+fabsf(yb.z-ya.z*rv.z)+fabsf(yb.w-ya.w*rv.w);
    float dx=xb.x-yb.x, dy=xb.y-yb.y, dz=xb.z-yb.z, dw=xb.w-yb.w;
    s3 += dx*dx+dy*dy+dz*dz+dw*dw;
  };
  auto hist4=[&](const float4 v){
    int i0h = __float2int_rn(v.x*255.0f); i0h = min(max(i0h,0),255);
    int i1h = __float2int_rn(v.y*255.0f); i1h = min(max(i1h,0),255);
    int i2h = __float2int_rn(v.z*255.0f); i2h = min(max(i2h,0),255);
    int i3h = __float2int_rn(v.w*255.0f); i3h = min(max(i3h,0),255);
    atomicAdd(&mysh[i0h],1u); atomicAdd(&mysh[i1h],1u);
    atomicAdd(&mysh[i2h],1u); atomicAdd(&mysh[i3h],1u);
  };

  // ---- init: rows i0..i0+6 (always inside [i0, eEnd): 7 < 16) ----
  #pragma unroll 1
  for(int r=i0; r<i0+7; ++r){
    float4 xa=*(const float4*)(xA + (size_t)r*W_ + c);
    float4 ya=*(const float4*)(yA + (size_t)r*W_ + c);
    float4 xb=*(const float4*)(xB + (size_t)r*W_ + c);
    float4 yb=*(const float4*)(yB + (size_t)r*W_ + c);
    float4 cv=*(const float4*)(c1b + (size_t)r*W_ + c);
    float4 rv=*(const float4*)(r1b + (size_t)r*W_ + c);
    upd5(AX,AY,AXX,AYY,AXY, xa,ya, 1.0f);
    upd5(BX,BY,BXX,BYY,BXY, xb,yb, 1.0f);
    elem_acc(xa,ya,xb,yb,cv,rv);
    if(do_c2){
      float4 c2v=*(const float4*)(c2b + (size_t)r*W_ + c);
      float ex=c2v.x-rv.x, ey=c2v.y-rv.y, ez=c2v.z-rv.z, ew=c2v.w-rv.w;
      s4 += ex*ex+ey*ey+ez*ez+ew*ew;
    }
    hist4(yb);
  }

  float accA=0.f, accB=0.f;
  auto hsum=[&](const float* p, float* h){
    float4 A=*(const float4*)p; float4 Bv=*(const float4*)(p+4);
    float2 D=*(const float2*)(p+8);
    float s=A.x+A.y+A.z+A.w+Bv.x+Bv.y+Bv.z;
    h[0]=s; s+=Bv.w-A.x; h[1]=s; s+=D.x-A.y; h[2]=s; s+=D.y-A.z; h[3]=s;
  };
  auto ssim_row=[&](int buf, float& out){
    float hx[4],hy[4],hxx[4],hyy[4],hxy[4];
    hsum(&S[buf][0][c], hx);
    hsum(&S[buf][1][c], hy);
    hsum(&S[buf][2][c], hxx);
    hsum(&S[buf][3][c], hyy);
    hsum(&S[buf][4][c], hxy);
    #pragma unroll
    for(int k=0;k<4;k++){
      if(c+k < OUTW){
        float ux=hx[k]*INV49, uy=hy[k]*INV49;
        float uxuy=ux*uy;
        float vx=COVN*(hxx[k]*INV49-ux*ux);
        float vy=COVN*(hyy[k]*INV49-uy*uy);
        float vxy=COVN*(hxy[k]*INV49-uxuy);
        float num=(2.f*uxuy+C1f)*(2.f*vxy+C2f);
        float den=(ux*ux+uy*uy+C1f)*(vx+vy+C2f);
        out += num/den;
      }
    }
  };

  // ---- main loop over output rows ----
  for(int i=i0; i<iEnd; ++i){
    *(float4*)&S[0][0][c]=AX; *(float4*)&S[0][1][c]=AY; *(float4*)&S[0][2][c]=AXX;
    *(float4*)&S[0][3][c]=AYY; *(float4*)&S[0][4][c]=AXY;
    *(float4*)&S[1][0][c]=BX; *(float4*)&S[1][1][c]=BY; *(float4*)&S[1][2][c]=BXX;
    *(float4*)&S[1][3][c]=BYY; *(float4*)&S[1][4][c]=BXY;

    const bool up = (i+1 < iEnd);
    const int  rn = i+7;
    const bool de = up && (rn < eEnd);
    float4 xan,yan,xbn,ybn,xao,yao,xbo,ybo,cv,rv,c2v;
    if(up){
      xan=*(const float4*)(xA + (size_t)rn*W_ + c);
      yan=*(const float4*)(yA + (size_t)rn*W_ + c);
      xbn=*(const float4*)(xB + (size_t)rn*W_ + c);
      ybn=*(const float4*)(yB + (size_t)rn*W_ + c);
      xao=*(const float4*)(xA + (size_t)i*W_ + c);
      yao=*(const float4*)(yA + (size_t)i*W_ + c);
      xbo=*(const float4*)(xB + (size_t)i*W_ + c);
      ybo=*(const float4*)(yB + (size_t)i*W_ + c);
    }
    if(de){
      cv=*(const float4*)(c1b + (size_t)rn*W_ + c);
      rv=*(const float4*)(r1b + (size_t)rn*W_ + c);
      if(do_c2) c2v=*(const float4*)(c2b + (size_t)rn*W_ + c);
    }
    __syncthreads();
    if(c < OUTW){
      ssim_row(0, accA);
      ssim_row(1, accB);
    }
    __syncthreads();
    if(up){
      upd5(AX,AY,AXX,AYY,AXY, xan,yan,  1.0f);
      upd5(AX,AY,AXX,AYY,AXY, xao,yao, -1.0f);
      upd5(BX,BY,BXX,BYY,BXY, xbn,ybn,  1.0f);
      upd5(BX,BY,BXX,BYY,BXY, xbo,ybo, -1.0f);
    }
    if(de){
      elem_acc(xan,yan,xbn,ybn,cv,rv);
      if(do_c2){
        float ex=c2v.x-rv.x, ey=c2v.y-rv.y, ez=c2v.z-rv.z, ew=c2v.w-rv.w;
        s4 += ex*ex+ey*ey+ez*ez+ew*ew;
      }
      hist4(ybn);
    }
  }

  // ---- block reduction + global merge ----
  float v[7]={s0,s1,s2,s3,s4,accA,accB};
  const int wid=t>>6, lane=t&63;
  #pragma unroll
  for(int k=0;k<7;k++){
    float r=wred(v[k]);
    if(lane==0) sred[wid][k]=r;
  }
  __syncthreads();
  if(t==0){
    atomicAdd(&acc[0],(double)(sred[0][0]+sred[1][0]));
    atomicAdd(&acc[1],(double)(sred[0][1]+sred[1][1]));
    atomicAdd(&acc[2],(double)(sred[0][2]+sred[1][2]));
    atomicAdd(&acc[3],(double)(sred[0][3]+sred[1][3]));
    atomicAdd(&acc[4],(double)(sred[0][4]+sred[1][4]));
    atomicAdd(&acc[6],(double)(sred[0][5]+sred[1][5]));
    atomicAdd(&acc[7],(double)(sred[0][6]+sred[1][6]));
  }
  for(int j=t; j<256; j+=128)
    atomicAdd(&bins[bc*256+j], hist[0][j]+hist[1][j]);
}

// ---------------- final combine ----------------
__global__ __launch_bounds__(256) void k_final(
    const float* __restrict__ chist, const float* __restrict__ score,
    const double* __restrict__ acc, const unsigned int* __restrict__ bins,
    float* __restrict__ out){
  const int tid = threadIdx.x;
  float cpart = 0.f;
  for(int i=tid; i<B_*C_*256; i+=256){
    float h = (float)bins[i] * (1.0f/(float)HW_);
    cpart += fabsf(chist[i]-h);
  }
  float gpart = 0.f;
  if(tid < B_){
    float x = -score[tid];
    gpart = (x > 0.f) ? (x + log1pf(expf(-x))) : log1pf(expf(x));
  }
  __shared__ float sc[4], sg[4];
  float rc=wred(cpart), rg=wred(gpart);
  const int wid=tid>>6, lane=tid&63;
  if(lane==0){ sc[wid]=rc; sg[wid]=rg; }
  __syncthreads();
  if(tid==0){
    float colorsum = sc[0]+sc[1]+sc[2]+sc[3];
    float gansum   = sg[0]+sg[1]+sg[2]+sg[3];
    double nfull = (double)NFULL;
    double m0 = acc[0]/nfull, m1 = acc[1]/nfull, m2 = acc[2]/nfull, mse = acc[3]/nfull;
    double light = acc[4]/(double)NHALF;
    double nss = (double)(B_*C_) * (double)OUTW * (double)OUTW;
    double ssimA = acc[6]/nss;   // comp0 vs real_comp0
    double ssimB = acc[7]/nss;   // img vs target
    float r_loss   = (float)((1.0-ssimA)+m0+m1+m2);
    float out_loss = (float)((1.0-ssimB)+mse);
    float color    = colorsum * (1.0f/(float)(B_*C_*256));
    float gan      = gansum * (1.0f/(float)B_);
    float lightf   = (float)light;
    float loss = r_loss + lightf + 0.1f*color + out_loss + 0.05f*gan;
    out[0]=loss; out[1]=loss; out[2]=r_loss; out[3]=lightf;
    out[4]=color; out[5]=out_loss; out[6]=gan;
  }
}

extern "C" void kernel_launch(void* const* d_in, const int* in_sizes, int n_in,
                              void* d_out, int out_size, void* d_ws, size_t ws_size,
                              hipStream_t stream) {
  const float* img    = (const float*)d_in[0];
  const float* target = (const float*)d_in[1];
  const float* comp0  = (const float*)d_in[2];
  const float* comp1  = (const float*)d_in[3];
  const float* comp2  = (const float*)d_in[4];
  const float* rc0    = (const float*)d_in[5];
  const float* rc1    = (const float*)d_in[6];
  const float* chist  = (const float*)d_in[7];
  const float* score  = (const float*)d_in[8];

  double* acc = (double*)d_ws;                                   // 8 doubles
  unsigned int* bins = (unsigned int*)((char*)d_ws + 128);       // 48*256 uints

  hipMemsetAsync(d_ws, 0, 128 + (size_t)B_*C_*256*4, stream);

  k_mega<<<48*NSTRIP, 128, 0, stream>>>(img, target, comp0, comp1, comp2,
                                        rc0, rc1, acc, bins);
  k_final<<<1, 256, 0, stream>>>(chist, score, acc, bins, (float*)d_out);
}